// Round 1
// baseline (4336.901 us; speedup 1.0000x reference)
//
#include <hip/hip_runtime.h>
#include <math.h>

// DeepSeekV3Mini fp32 baseline implementation.
// B=2 S=1024 V=32000 D=768 H=12 HD=64 DFF=3072 E=8 K(top)=2 DL=192 L=2 ROPE=64
//
// Workspace layout (~90 MB floats) — all buffers rewritten every launch.

namespace {

constexpr int kB = 2;
constexpr int kS = 1024;
constexpr int kV = 32000;
constexpr int kD = 768;
constexpr int kH = 12;
constexpr int kHD = 64;
constexpr int kDFF = 3072;
constexpr int kE = 8;
constexpr int kDL = 192;
constexpr int kL = 2;
constexpr int kTok = kB * kS;  // 2048

__device__ __forceinline__ float geluf(float x) {
  // jax.nn.gelu default (approximate=True): 0.5x(1+tanh(sqrt(2/pi)(x+0.044715x^3)))
  float x3 = x * x * x;
  return 0.5f * x * (1.0f + tanhf(0.7978845608028654f * (x + 0.044715f * x3)));
}

// ---------------- embedding gather ----------------
__global__ void k_embed(const int* __restrict__ ids, const float* __restrict__ emb,
                        float* __restrict__ x) {
  int t = blockIdx.x;
  int id = ids[t];
  const float4* src = (const float4*)(emb + (size_t)id * kD);
  float4* dst = (float4*)(x + (size_t)t * kD);
  for (int i = threadIdx.x; i < kD / 4; i += blockDim.x) dst[i] = src[i];
}

// ---------------- layernorm (one block per row, D=768, 256 thr) ----------------
__global__ __launch_bounds__(256) void k_ln(const float* __restrict__ x,
                                            const float* __restrict__ g,
                                            const float* __restrict__ b,
                                            float* __restrict__ out) {
  int row = blockIdx.x;
  const float* xr = x + (size_t)row * kD;
  __shared__ float red[8];
  int tid = threadIdx.x;
  float v0 = xr[tid * 3 + 0], v1 = xr[tid * 3 + 1], v2 = xr[tid * 3 + 2];
  float s = v0 + v1 + v2;
#pragma unroll
  for (int off = 32; off >= 1; off >>= 1) s += __shfl_down(s, off);
  if ((tid & 63) == 0) red[tid >> 6] = s;
  __syncthreads();
  if (tid == 0) red[4] = (red[0] + red[1] + red[2] + red[3]) * (1.0f / kD);
  __syncthreads();
  float mean = red[4];
  float d0 = v0 - mean, d1 = v1 - mean, d2 = v2 - mean;
  float sv = d0 * d0 + d1 * d1 + d2 * d2;
#pragma unroll
  for (int off = 32; off >= 1; off >>= 1) sv += __shfl_down(sv, off);
  if ((tid & 63) == 0) red[tid >> 6] = sv;
  __syncthreads();
  if (tid == 0) red[5] = (red[0] + red[1] + red[2] + red[3]) * (1.0f / kD);
  __syncthreads();
  float rstd = rsqrtf(red[5] + 1e-6f);
  int c = tid * 3;
  float* orow = out + (size_t)row * kD;
  orow[c + 0] = d0 * rstd * g[c + 0] + b[c + 0];
  orow[c + 1] = d1 * rstd * g[c + 1] + b[c + 1];
  orow[c + 2] = d2 * rstd * g[c + 2] + b[c + 2];
}

// ---------------- generic 64x64 tiled GEMM, BK=16, 256 thr, 4x4 micro-tile ----
// MODE 0: C = A@B            (plain store)
// MODE 1: C += A@B           (residual add)
// MODE 2: MoE1: rows gathered via tok[], C[row] = gelu(A@B + bias)   (per expert z)
// MODE 3: MoE2: compact rows, atomicAdd into C[tok[row]] += wgt[row]*(A@B+bias)
template <int MODE>
__global__ __launch_bounds__(256) void k_gemm(
    const float* __restrict__ A, const float* __restrict__ Bm, float* __restrict__ C,
    int M, int N, int K, const float* __restrict__ bias, const int* __restrict__ tok,
    const float* __restrict__ wgt, const int* __restrict__ cnt,
    const int* __restrict__ eoff) {
  __shared__ float As[16][68];
  __shared__ float Bs[16][68];
  const int tid = threadIdx.x;
  const int tx = tid & 15, ty = tid >> 4;
  const int n0 = blockIdx.x * 64;
  const int m0 = blockIdx.y * 64;
  int nrows = M;
  int base = 0;
  if (MODE >= 2) {
    int e = blockIdx.z;
    nrows = cnt[e];
    if (m0 >= nrows) return;
    base = eoff[e];
    Bm += (size_t)e * K * N;
    bias += (size_t)e * N;
  }
  const int la_r = tid >> 2;        // 0..63 row in tile (A load)
  const int la_k = (tid & 3) * 4;   // 0..12 k offset   (A load)
  const int lb_k = tid >> 4;        // 0..15            (B load)
  const int lb_n = (tid & 15) * 4;  // 0..60            (B load)
  const float* Arow = nullptr;
  {
    int r = m0 + la_r;
    if (MODE == 2) {
      if (r < nrows) Arow = A + (size_t)tok[base + r] * K;
    } else if (MODE == 3) {
      if (r < nrows) Arow = A + (size_t)(base + r) * K;
    } else {
      Arow = A + (size_t)r * K;
    }
  }
  float acc[4][4] = {};
  for (int k0 = 0; k0 < K; k0 += 16) {
    float4 av = make_float4(0.f, 0.f, 0.f, 0.f);
    if (Arow) av = *(const float4*)(Arow + k0 + la_k);
    float4 bv = *(const float4*)(Bm + (size_t)(k0 + lb_k) * N + n0 + lb_n);
    __syncthreads();
    As[la_k + 0][la_r] = av.x;
    As[la_k + 1][la_r] = av.y;
    As[la_k + 2][la_r] = av.z;
    As[la_k + 3][la_r] = av.w;
    *(float4*)&Bs[lb_k][lb_n] = bv;
    __syncthreads();
#pragma unroll
    for (int kk = 0; kk < 16; kk++) {
      float4 a4 = *(const float4*)&As[kk][ty * 4];
      float4 b4 = *(const float4*)&Bs[kk][tx * 4];
      float ar[4] = {a4.x, a4.y, a4.z, a4.w};
      float br[4] = {b4.x, b4.y, b4.z, b4.w};
#pragma unroll
      for (int i = 0; i < 4; i++)
#pragma unroll
        for (int j = 0; j < 4; j++) acc[i][j] += ar[i] * br[j];
    }
  }
  if (MODE == 0) {
#pragma unroll
    for (int i = 0; i < 4; i++) {
      float* cp = C + (size_t)(m0 + ty * 4 + i) * N + n0 + tx * 4;
      *(float4*)cp = make_float4(acc[i][0], acc[i][1], acc[i][2], acc[i][3]);
    }
  } else if (MODE == 1) {
#pragma unroll
    for (int i = 0; i < 4; i++) {
      float* cp = C + (size_t)(m0 + ty * 4 + i) * N + n0 + tx * 4;
      float4 o4 = *(float4*)cp;
      o4.x += acc[i][0]; o4.y += acc[i][1]; o4.z += acc[i][2]; o4.w += acc[i][3];
      *(float4*)cp = o4;
    }
  } else if (MODE == 2) {
#pragma unroll
    for (int i = 0; i < 4; i++) {
      int r = m0 + ty * 4 + i;
      if (r < nrows) {
        float* cp = C + (size_t)(base + r) * N + n0 + tx * 4;
#pragma unroll
        for (int j = 0; j < 4; j++) cp[j] = geluf(acc[i][j] + bias[n0 + tx * 4 + j]);
      }
    }
  } else {  // MODE 3
#pragma unroll
    for (int i = 0; i < 4; i++) {
      int r = m0 + ty * 4 + i;
      if (r < nrows) {
        int t = tok[base + r];
        float w = wgt[base + r];
        float* cp = C + (size_t)t * N + n0 + tx * 4;
#pragma unroll
        for (int j = 0; j < 4; j++)
          atomicAdd(cp + j, w * (acc[i][j] + bias[n0 + tx * 4 + j]));
      }
    }
  }
}

// ---------------- RoPE tables (computed on device each launch; tiny) ----------
__global__ void k_ropetab(float* __restrict__ cost, float* __restrict__ sint) {
  int i = blockIdx.x * blockDim.x + threadIdx.x;
  if (i >= kS * 32) return;
  int s = i >> 5, f = i & 31;
  float invf = powf(10000.0f, -(float)f / 32.0f);
  float a = (float)s * invf;
  cost[i] = cosf(a);
  sint[i] = sinf(a);
}

// ---------------- RoPE apply (in place; ROPE==HD==64 so whole head rotates) ---
__global__ void k_rope(float* __restrict__ x, const float* __restrict__ cost,
                       const float* __restrict__ sint) {
  int i = blockIdx.x * blockDim.x + threadIdx.x;
  if (i >= kTok * kH * 32) return;
  int d = i & 31;
  int h = (i >> 5) % kH;
  int t = i / (32 * kH);
  int s = t & (kS - 1);
  float c = cost[s * 32 + d], sn = sint[s * 32 + d];
  float* row = x + (size_t)t * kD + h * kHD;
  float x1 = row[d], x2 = row[d + 32];
  row[d] = x1 * c - x2 * sn;
  row[d + 32] = x2 * c + x1 * sn;
}

// ---------------- flash attention fp32, Qtile=64, Ktile=64, 256 thr -----------
__global__ __launch_bounds__(256) void k_attn(const float* __restrict__ q,
                                              const float* __restrict__ kk_,
                                              const float* __restrict__ v,
                                              float* __restrict__ o) {
  __shared__ float Qt[64][68];
  __shared__ float Kt[64][68];  // reused as P after scores are consumed
  __shared__ float Vt[64][68];
  const int qt = blockIdx.x, hh = blockIdx.y, bb = blockIdx.z;
  const int tid = threadIdx.x;
  const int tx = tid & 15, ty = tid >> 4;
  const size_t baseoff = ((size_t)bb * kS) * kD + (size_t)hh * kHD;
  const int lr = tid >> 2;        // 0..63
  const int lc = (tid & 3) * 16;  // 0,16,32,48
  {
    const float* src = q + baseoff + (size_t)(qt * 64 + lr) * kD + lc;
#pragma unroll
    for (int j = 0; j < 16; j += 4) {
      float4 t4 = *(const float4*)(src + j);
      t4.x *= 0.125f; t4.y *= 0.125f; t4.z *= 0.125f; t4.w *= 0.125f;  // 1/sqrt(64)
      *(float4*)&Qt[lr][lc + j] = t4;
    }
  }
  float m[4], l[4], oacc[4][4];
#pragma unroll
  for (int i = 0; i < 4; i++) {
    m[i] = -INFINITY;
    l[i] = 0.f;
#pragma unroll
    for (int j = 0; j < 4; j++) oacc[i][j] = 0.f;
  }
  for (int kt = 0; kt <= qt; kt++) {
    __syncthreads();  // prev iter done reading Kt(P)/Vt; Q tile visible on first iter
    {
      const float* ks = kk_ + baseoff + (size_t)(kt * 64 + lr) * kD + lc;
      const float* vs = v + baseoff + (size_t)(kt * 64 + lr) * kD + lc;
#pragma unroll
      for (int j = 0; j < 16; j += 4) {
        *(float4*)&Kt[lr][lc + j] = *(const float4*)(ks + j);
        *(float4*)&Vt[lr][lc + j] = *(const float4*)(vs + j);
      }
    }
    __syncthreads();
    float s[4][4] = {};
#pragma unroll
    for (int d = 0; d < 64; d += 4) {
      float4 q0 = *(const float4*)&Qt[ty * 4 + 0][d];
      float4 q1 = *(const float4*)&Qt[ty * 4 + 1][d];
      float4 q2 = *(const float4*)&Qt[ty * 4 + 2][d];
      float4 q3 = *(const float4*)&Qt[ty * 4 + 3][d];
      float4 k0 = *(const float4*)&Kt[tx * 4 + 0][d];
      float4 k1 = *(const float4*)&Kt[tx * 4 + 1][d];
      float4 k2 = *(const float4*)&Kt[tx * 4 + 2][d];
      float4 k3 = *(const float4*)&Kt[tx * 4 + 3][d];
      float qs[4][4] = {{q0.x, q0.y, q0.z, q0.w}, {q1.x, q1.y, q1.z, q1.w},
                        {q2.x, q2.y, q2.z, q2.w}, {q3.x, q3.y, q3.z, q3.w}};
      float ks2[4][4] = {{k0.x, k0.y, k0.z, k0.w}, {k1.x, k1.y, k1.z, k1.w},
                         {k2.x, k2.y, k2.z, k2.w}, {k3.x, k3.y, k3.z, k3.w}};
#pragma unroll
      for (int i = 0; i < 4; i++)
#pragma unroll
        for (int j = 0; j < 4; j++)
          s[i][j] += qs[i][0] * ks2[j][0] + qs[i][1] * ks2[j][1] +
                     qs[i][2] * ks2[j][2] + qs[i][3] * ks2[j][3];
    }
    if (kt == qt) {
#pragma unroll
      for (int i = 0; i < 4; i++)
#pragma unroll
        for (int j = 0; j < 4; j++)
          if (tx * 4 + j > ty * 4 + i) s[i][j] = -INFINITY;
    }
    // online softmax; rows owned by 16-lane tx-groups
#pragma unroll
    for (int i = 0; i < 4; i++) {
      float rmax = fmaxf(fmaxf(s[i][0], s[i][1]), fmaxf(s[i][2], s[i][3]));
#pragma unroll
      for (int msk = 1; msk < 16; msk <<= 1) rmax = fmaxf(rmax, __shfl_xor(rmax, msk));
      float mnew = fmaxf(m[i], rmax);
      float corr = __expf(m[i] - mnew);
      float rsum = 0.f;
#pragma unroll
      for (int j = 0; j < 4; j++) {
        float p = __expf(s[i][j] - mnew);
        s[i][j] = p;
        rsum += p;
      }
#pragma unroll
      for (int msk = 1; msk < 16; msk <<= 1) rsum += __shfl_xor(rsum, msk);
      l[i] = l[i] * corr + rsum;
      m[i] = mnew;
#pragma unroll
      for (int j = 0; j < 4; j++) oacc[i][j] *= corr;
    }
    __syncthreads();  // all done reading Kt for scores
#pragma unroll
    for (int i = 0; i < 4; i++)
      *(float4*)&Kt[ty * 4 + i][tx * 4] =
          make_float4(s[i][0], s[i][1], s[i][2], s[i][3]);
    __syncthreads();
    // PV accumulate
#pragma unroll
    for (int c = 0; c < 64; c += 4) {
      float4 p0 = *(const float4*)&Kt[ty * 4 + 0][c];
      float4 p1 = *(const float4*)&Kt[ty * 4 + 1][c];
      float4 p2 = *(const float4*)&Kt[ty * 4 + 2][c];
      float4 p3 = *(const float4*)&Kt[ty * 4 + 3][c];
      float4 w0 = *(const float4*)&Vt[c + 0][tx * 4];
      float4 w1 = *(const float4*)&Vt[c + 1][tx * 4];
      float4 w2 = *(const float4*)&Vt[c + 2][tx * 4];
      float4 w3 = *(const float4*)&Vt[c + 3][tx * 4];
      float ps[4][4] = {{p0.x, p0.y, p0.z, p0.w}, {p1.x, p1.y, p1.z, p1.w},
                        {p2.x, p2.y, p2.z, p2.w}, {p3.x, p3.y, p3.z, p3.w}};
      float vs2[4][4] = {{w0.x, w0.y, w0.z, w0.w}, {w1.x, w1.y, w1.z, w1.w},
                         {w2.x, w2.y, w2.z, w2.w}, {w3.x, w3.y, w3.z, w3.w}};
#pragma unroll
      for (int i = 0; i < 4; i++)
#pragma unroll
        for (int j = 0; j < 4; j++)
          oacc[i][j] += ps[i][0] * vs2[0][j] + ps[i][1] * vs2[1][j] +
                        ps[i][2] * vs2[2][j] + ps[i][3] * vs2[3][j];
    }
  }
#pragma unroll
  for (int i = 0; i < 4; i++) {
    float inv = 1.0f / l[i];
    float* op = o + baseoff + (size_t)(qt * 64 + ty * 4 + i) * kD + tx * 4;
    *(float4*)op = make_float4(oacc[i][0] * inv, oacc[i][1] * inv,
                               oacc[i][2] * inv, oacc[i][3] * inv);
  }
}

// ---------------- MoE routing: gates softmax + top2 + counts ------------------
__global__ void k_route(const float* __restrict__ h2, const float* __restrict__ Wg,
                        int* __restrict__ eidx, float* __restrict__ ew,
                        int* __restrict__ cnt) {
  int t = blockIdx.x;
  int lane = threadIdx.x;  // 64 threads = 1 wave
  int e = lane & 7;
  int dstart = lane >> 3;  // 0..7
  const float* hr = h2 + (size_t)t * kD;
  float sum = 0.f;
  for (int d = dstart; d < kD; d += 8) sum += hr[d] * Wg[d * kE + e];
  sum += __shfl_xor(sum, 8);
  sum += __shfl_xor(sum, 16);
  sum += __shfl_xor(sum, 32);
  float lg[8];
#pragma unroll
  for (int i = 0; i < 8; i++) lg[i] = __shfl(sum, i);
  if (lane == 0) {
    int i0 = 0;
    float v0 = lg[0];
    for (int i = 1; i < 8; i++)
      if (lg[i] > v0) { v0 = lg[i]; i0 = i; }
    int i1 = -1;
    float v1 = -INFINITY;
    for (int i = 0; i < 8; i++)
      if (i != i0 && lg[i] > v1) { v1 = lg[i]; i1 = i; }
    float e1 = __expf(v1 - v0);
    float inv = 1.0f / (1.0f + e1);
    eidx[t * 2] = i0;
    eidx[t * 2 + 1] = i1;
    ew[t * 2] = inv;
    ew[t * 2 + 1] = e1 * inv;
    atomicAdd(&cnt[i0], 1);
    atomicAdd(&cnt[i1], 1);
  }
}

__global__ void k_scan(const int* __restrict__ cnt, int* __restrict__ eoff,
                       int* __restrict__ cnt2) {
  if (threadIdx.x == 0) {
    int s = 0;
    for (int e = 0; e < kE; e++) {
      eoff[e] = s;
      s += cnt[e];
    }
  }
  if (threadIdx.x < kE) cnt2[threadIdx.x] = 0;
}

__global__ void k_assign(const int* __restrict__ eidx, const float* __restrict__ ew,
                         const int* __restrict__ eoff, int* __restrict__ cnt2,
                         int* __restrict__ tok, float* __restrict__ wgt) {
  int t = blockIdx.x * blockDim.x + threadIdx.x;
  if (t >= kTok) return;
#pragma unroll
  for (int s = 0; s < 2; s++) {
    int e = eidx[t * 2 + s];
    float w = ew[t * 2 + s];
    int p = atomicAdd(&cnt2[e], 1);
    int row = eoff[e] + p;
    tok[row] = t;
    wgt[row] = w;
  }
}

}  // namespace

extern "C" void kernel_launch(void* const* d_in, const int* in_sizes, int n_in,
                              void* d_out, int out_size, void* d_ws, size_t ws_size,
                              hipStream_t stream) {
  const int* ids = (const int*)d_in[0];
  const float* emb = (const float*)d_in[1];
  const float* ln1_g = (const float*)d_in[2];
  const float* ln1_b = (const float*)d_in[3];
  const float* ln2_g = (const float*)d_in[4];
  const float* ln2_b = (const float*)d_in[5];
  const float* Wq = (const float*)d_in[6];
  const float* Wkv = (const float*)d_in[7];
  const float* Wk = (const float*)d_in[8];
  const float* Wv = (const float*)d_in[9];
  const float* Wo = (const float*)d_in[10];
  const float* Wg = (const float*)d_in[11];
  const float* W1 = (const float*)d_in[12];
  const float* b1 = (const float*)d_in[13];
  const float* W2 = (const float*)d_in[14];
  const float* b2 = (const float*)d_in[15];
  const float* lnf_g = (const float*)d_in[16];
  const float* lnf_b = (const float*)d_in[17];
  const float* Wout = (const float*)d_in[18];
  float* out = (float*)d_out;

  float* ws = (float*)d_ws;
  size_t off = 0;
  auto alloc = [&](size_t n) {
    float* p = ws + off;
    off += (n + 3) & ~(size_t)3;
    return p;
  };
  float* x = alloc((size_t)kTok * kD);
  float* h = alloc((size_t)kTok * kD);
  float* qb = alloc((size_t)kTok * kD);
  float* kb = alloc((size_t)kTok * kD);
  float* vb = alloc((size_t)kTok * kD);
  float* attno = alloc((size_t)kTok * kD);
  float* lat = alloc((size_t)kTok * kDL);
  float* cost = alloc((size_t)kS * 32);
  float* sint = alloc((size_t)kS * 32);
  float* hff = alloc((size_t)kTok * 2 * kDFF);  // compact (token,slot) rows
  float* ew = alloc((size_t)kTok * 2);
  float* wgt = alloc((size_t)kTok * 2);
  int* eidx = (int*)alloc((size_t)kTok * 2);
  int* tok = (int*)alloc((size_t)kTok * 2);
  int* cnt = (int*)alloc(8);
  int* cnt2 = (int*)alloc(8);
  int* eoff = (int*)alloc(8);
  (void)ws_size;  // requires ~90 MB; assumed available

  k_ropetab<<<(kS * 32 + 255) / 256, 256, 0, stream>>>(cost, sint);
  k_embed<<<kTok, 192, 0, stream>>>(ids, emb, x);

  for (int l = 0; l < kL; l++) {
    k_ln<<<kTok, 256, 0, stream>>>(x, ln1_g + l * kD, ln1_b + l * kD, h);
    k_gemm<0><<<dim3(kD / 64, kTok / 64), 256, 0, stream>>>(
        h, Wq + (size_t)l * kD * kD, qb, kTok, kD, kD, nullptr, nullptr, nullptr,
        nullptr, nullptr);
    k_gemm<0><<<dim3(kDL / 64, kTok / 64), 256, 0, stream>>>(
        h, Wkv + (size_t)l * kD * kDL, lat, kTok, kDL, kD, nullptr, nullptr, nullptr,
        nullptr, nullptr);
    k_gemm<0><<<dim3(kD / 64, kTok / 64), 256, 0, stream>>>(
        lat, Wk + (size_t)l * kDL * kD, kb, kTok, kD, kDL, nullptr, nullptr, nullptr,
        nullptr, nullptr);
    k_gemm<0><<<dim3(kD / 64, kTok / 64), 256, 0, stream>>>(
        lat, Wv + (size_t)l * kDL * kD, vb, kTok, kD, kDL, nullptr, nullptr, nullptr,
        nullptr, nullptr);
    k_rope<<<(kTok * kH * 32 + 255) / 256, 256, 0, stream>>>(qb, cost, sint);
    k_rope<<<(kTok * kH * 32 + 255) / 256, 256, 0, stream>>>(kb, cost, sint);
    k_attn<<<dim3(kS / 64, kH, kB), 256, 0, stream>>>(qb, kb, vb, attno);
    k_gemm<1><<<dim3(kD / 64, kTok / 64), 256, 0, stream>>>(
        attno, Wo + (size_t)l * kD * kD, x, kTok, kD, kD, nullptr, nullptr, nullptr,
        nullptr, nullptr);
    k_ln<<<kTok, 256, 0, stream>>>(x, ln2_g + l * kD, ln2_b + l * kD, h);
    hipMemsetAsync(cnt, 0, kE * sizeof(int), stream);
    k_route<<<kTok, 64, 0, stream>>>(h, Wg + (size_t)l * kD * kE, eidx, ew, cnt);
    k_scan<<<1, 64, 0, stream>>>(cnt, eoff, cnt2);
    k_assign<<<(kTok + 255) / 256, 256, 0, stream>>>(eidx, ew, eoff, cnt2, tok, wgt);
    k_gemm<2><<<dim3(kDFF / 64, kTok / 64, kE), 256, 0, stream>>>(
        h, W1 + (size_t)l * kE * kD * kDFF, hff, kTok, kDFF, kD,
        b1 + (size_t)l * kE * kDFF, tok, nullptr, cnt, eoff);
    k_gemm<3><<<dim3(kD / 64, kTok / 64, kE), 256, 0, stream>>>(
        hff, W2 + (size_t)l * kE * kDFF * kD, x, kTok, kD, kDFF,
        b2 + (size_t)l * kE * kD, tok, wgt, cnt, eoff);
  }
  k_ln<<<kTok, 256, 0, stream>>>(x, lnf_g, lnf_b, h);
  k_gemm<0><<<dim3(kV / 64, kTok / 64), 256, 0, stream>>>(
      h, Wout, out, kTok, kV, kD, nullptr, nullptr, nullptr, nullptr, nullptr);
}